// Round 10
// baseline (108.048 us; speedup 1.0000x reference)
//
#include <hip/hip_runtime.h>

// etp: out[n, coff(l3)+m3, u] = sum_p sum_{m1,m2} cg_p[m1,m2,m3] * Y[n, yoff(l1)+m1]
//                               * H[n, coff(l2)+m2, u] * W[n, p, u]
// N=16384 edges, 16 channels (l=0..3, dims 1,3,5,7), MUL=128.
//
// R9: LDS-issue-rate fix. R8's arithmetic closed: 158 ds_read_b128/thread
// x 128 waves/CU x ~12cyc = 101us = measured dur. So: float4 over u
// (4 u/thread, 32 lanes/edge -> one wave serves 2 edges, 2-addr broadcast
// reads are conflict-free) cuts LDS wave-instructions 4x -> ~25us.
// Register blowup avoided via R8's l2-grouping: only hh[d2<=7] live at a
// time (persistent set = acc[16] f4 = 64 regs; peak ~116 < 128 cap from
// __launch_bounds__(256,4)).

#define BS 256
#define GSZ 32    // lanes per edge
#define EPB 8     // edges per block
#define YD 16
#define HD 2048
#define WD 2944
#define NROW 99   // sum of d3 over paths (B rows, padded to 8 floats)

typedef float f4 __attribute__((ext_vector_type(4)));

// X(p, l1, l2, l3, cg_offset, row_offset) — for the build phase
#define FOR_PATHS(X) \
  X(0, 0,0,0,    0,  0) \
  X(1, 0,1,1,    1,  1) \
  X(2, 0,2,2,   10,  4) \
  X(3, 0,3,3,   35,  9) \
  X(4, 1,0,1,   84, 16) \
  X(5, 1,1,0,   93, 19) \
  X(6, 1,1,2,  102, 20) \
  X(7, 1,2,1,  147, 25) \
  X(8, 1,2,3,  192, 28) \
  X(9, 1,3,2,  297, 35) \
  X(10,2,0,2,  402, 40) \
  X(11,2,1,1,  427, 45) \
  X(12,2,1,3,  472, 48) \
  X(13,2,2,0,  577, 55) \
  X(14,2,2,2,  602, 56) \
  X(15,2,3,1,  727, 61) \
  X(16,2,3,3,  832, 64) \
  X(17,3,0,3, 1077, 71) \
  X(18,3,1,2, 1126, 78) \
  X(19,3,2,1, 1231, 83) \
  X(20,3,2,3, 1336, 86) \
  X(21,3,3,0, 1581, 93) \
  X(22,3,3,2, 1630, 94)

__host__ __device__ constexpr int coff(int l) {
  return l == 0 ? 0 : (l == 1 ? 1 : (l == 2 ? 4 : 9));
}

__global__ __launch_bounds__(BS, 4) void etp_kernel(
    const float* __restrict__ Y, const float* __restrict__ H,
    const float* __restrict__ W, const float* __restrict__ CG,
    float* __restrict__ O) {
  const int g = threadIdx.x >> 5;   // edge within block
  const int l = threadIdx.x & 31;   // lane within edge-group; owns u = 4l..4l+3
  const size_t n = (size_t)blockIdx.x * EPB + g;

  __shared__ __align__(16) float Bsm[EPB][NROW * 8];  // 25344 B
  __shared__ float ysm[EPB][YD];

  { const int t = threadIdx.x;
    if (t < EPB * YD) {
      const int e = t >> 4, c = t & 15;
      ysm[e][c] = Y[(size_t)(blockIdx.x * EPB + e) * YD + c];
    } }
  __syncthreads();

  // Phase 1: B_p[m3][m2] = sum_a cg_p[a,m2,m3] * y[coff(l1)+a], per edge.
#define BUILD(P, L1, L2, L3, CGO, RO) { \
    constexpr int d1 = 2*(L1)+1, d2 = 2*(L2)+1, d3 = 2*(L3)+1; \
    _Pragma("unroll") \
    for (int it = 0; it < (d2 * d3 + GSZ - 1) / GSZ; ++it) { \
      const int idx = l + it * GSZ; \
      if (idx < d2 * d3) { \
        const int m3 = idx / d2, m2 = idx - m3 * d2; \
        float s = 0.f; \
        _Pragma("unroll") \
        for (int a = 0; a < d1; ++a) \
          s += CG[(CGO) + (a * d2 + m2) * d3 + m3] * ysm[g][coff(L1) + a]; \
        Bsm[g][((RO) + m3) * 8 + m2] = s; \
      } } }
  FOR_PATHS(BUILD)
#undef BUILD
  __syncthreads();

  // Phase 2: float4 per-lane contraction, paths grouped by l2 so only
  // hh[d2] is live at a time (persistent set = acc[16]).
  const f4* __restrict__ Hp = (const f4*)(H + n * HD);
  const f4* __restrict__ Wp = (const f4*)(W + n * WD);
  f4* __restrict__ Op = (f4*)(O + n * HD);

  f4 acc[YD];
#pragma unroll
  for (int c = 0; c < YD; ++c) acc[c] = (f4)0.f;

#define DOP(P, L2, L3, RO) { \
    constexpr int d2 = 2*(L2)+1, d3 = 2*(L3)+1; \
    const f4 wv = Wp[(P) * GSZ + l]; \
    _Pragma("unroll") \
    for (int m3 = 0; m3 < d3; ++m3) { \
      const f4* row = (const f4*)&Bsm[g][((RO) + m3) * 8]; \
      float br[8]; \
      *(f4*)&br[0] = row[0]; \
      if (d2 > 4) *(f4*)&br[4] = row[1]; \
      f4 s = (f4)0.f; \
      _Pragma("unroll") \
      for (int m2 = 0; m2 < d2; ++m2) s += br[m2] * hh[m2]; \
      acc[coff(L3) + m3] += s * wv; \
    } }

  { // l2 = 0: paths 0,4,10,17
    f4 hh[1];
    hh[0] = Hp[(coff(0) + 0) * GSZ + l];
    DOP(0, 0, 0, 0)  DOP(4, 0, 1, 16)  DOP(10, 0, 2, 40)  DOP(17, 0, 3, 71)
  }
  { // l2 = 1: paths 1,5,6,11,12,18
    f4 hh[3];
#pragma unroll
    for (int m = 0; m < 3; ++m) hh[m] = Hp[(coff(1) + m) * GSZ + l];
    DOP(1, 1, 1, 1)  DOP(5, 1, 0, 19)  DOP(6, 1, 2, 20)
    DOP(11, 1, 1, 45)  DOP(12, 1, 3, 48)  DOP(18, 1, 2, 78)
  }
  { // l2 = 2: paths 2,7,8,13,14,19,20
    f4 hh[5];
#pragma unroll
    for (int m = 0; m < 5; ++m) hh[m] = Hp[(coff(2) + m) * GSZ + l];
    DOP(2, 2, 2, 4)  DOP(7, 2, 1, 25)  DOP(8, 2, 3, 28)
    DOP(13, 2, 0, 55)  DOP(14, 2, 2, 56)  DOP(19, 2, 1, 83)  DOP(20, 2, 3, 86)
  }
  { // l2 = 3: paths 3,9,15,16,21,22
    f4 hh[7];
#pragma unroll
    for (int m = 0; m < 7; ++m) hh[m] = Hp[(coff(3) + m) * GSZ + l];
    DOP(3, 3, 3, 9)  DOP(9, 3, 2, 35)  DOP(15, 3, 1, 61)
    DOP(16, 3, 3, 64)  DOP(21, 3, 0, 93)  DOP(22, 3, 2, 94)
  }
#undef DOP

#pragma unroll
  for (int c = 0; c < YD; ++c)
    __builtin_nontemporal_store(acc[c], &Op[c * GSZ + l]);
}

extern "C" void kernel_launch(void* const* d_in, const int* in_sizes, int n_in,
                              void* d_out, int out_size, void* d_ws, size_t ws_size,
                              hipStream_t stream) {
  const float* Y  = (const float*)d_in[0];
  const float* H  = (const float*)d_in[1];
  const float* W  = (const float*)d_in[2];
  const float* CG = (const float*)d_in[3];
  float* O = (float*)d_out;

  const int n_edges = in_sizes[0] / YD;        // 16384
  etp_kernel<<<n_edges / EPB, BS, 0, stream>>>(Y, H, W, CG, O);
}